// Round 17
// baseline (139.032 us; speedup 1.0000x reference)
//
#include <hip/hip_runtime.h>
#include <hip/hip_bf16.h>
#include <stdint.h>
#include <stddef.h>

#define DIM 1024
#define SEQ 2048
#define KF 24

using f32x4    = __attribute__((ext_vector_type(4))) float;
using bf16x8   = __attribute__((ext_vector_type(8))) short;
using uint32x4 = __attribute__((ext_vector_type(4))) unsigned int;

__device__ __forceinline__ unsigned short f2bf(float f){
  union { float f; unsigned int i; } v; v.f = f;
  unsigned int r = v.i + 0x7FFFu + ((v.i >> 16) & 1u);  // RNE
  return (unsigned short)(r >> 16);
}
// D = a.bf16[0]*b.bf16[0] + a.bf16[1]*b.bf16[1] + c   (V_DOT2_F32_BF16, VOP3P)
__device__ __forceinline__ float dot2bf(unsigned int a, unsigned int b, float c){
  float d;
  asm("v_dot2_f32_bf16 %0, %1, %2, %3" : "=v"(d) : "v"(a), "v"(b), "v"(c));
  return d;
}
__device__ __forceinline__ unsigned vext(const uint32x4 v, int i){
  return i == 0 ? v.x : i == 1 ? v.y : i == 2 ? v.z : v.w;
}
__device__ __forceinline__ void gload_lds16(const void* g, void* l){
  __builtin_amdgcn_global_load_lds(
      (const __attribute__((address_space(1))) unsigned int*)g,
      (__attribute__((address_space(3))) unsigned int*)l, 16, 0, 0);
}
__device__ __forceinline__ uint32x4 make_srsrc(const void* base, unsigned bytes){
  uint32x4 r;
  r.x = (unsigned)(uintptr_t)base;
  r.y = (unsigned)((uintptr_t)base >> 32);   // stride=0
  r.z = bytes;                               // num_records (bytes); OOB loads -> 0
  r.w = 0x00020000u;                         // raw untyped dword
  return r;
}

// ---------------- prep: x fp32 -> bf16 ----------------
__global__ void k_cvt_x(const float* __restrict__ x, unsigned short* __restrict__ xb){
  int i = blockIdx.x * 256 + threadIdx.x;            // each thread 4 elems
  const float4* x4 = (const float4*)x;
  float4 v = x4[i];
  ushort4 o;
  o.x = f2bf(v.x); o.y = f2bf(v.y); o.z = f2bf(v.z); o.w = f2bf(v.w);
  *(ushort4*)(xb + (size_t)i * 4) = o;
}

// ---------------- prep: M_inputs transpose -> bf16 (B^T, [d][e]) ----------------
__global__ void k_tr_M(const float* __restrict__ Mi, unsigned short* __restrict__ MbT){
  __shared__ float tile[32][33];
  int e0 = blockIdx.y * 32, d0 = blockIdx.x * 32;
  int tx = threadIdx.x, ty = threadIdx.y;            // block (32,8)
  #pragma unroll
  for (int r = 0; r < 32; r += 8)
    tile[ty + r][tx] = Mi[(size_t)(e0 + ty + r) * DIM + d0 + tx];
  __syncthreads();
  #pragma unroll
  for (int r = 0; r < 32; r += 8)
    MbT[(size_t)(d0 + ty + r) * DIM + e0 + tx] = f2bf(tile[tx][ty + r]);
}

// ---------------- prep: pe packed pairs, TRANSPOSED [d][512] ----------------
// pepkT[d][r2] = u32{ lo = 2*phi[4*r2][d], hi = 2*phi[4*r2+2][d] } = (pe[2r2], pe[2r2+1])
__global__ void k_pe(const float* __restrict__ filters, const float* __restrict__ Mf,
                     unsigned int* __restrict__ pepkT){
  int r2 = blockIdx.x * 256 + threadIdx.x;           // 0..511 (grid.x = 2)
  int d  = blockIdx.y;                               // 0..1023
  float a0 = 0.f, a1 = 0.f;
  #pragma unroll
  for (int k = 0; k < KF; ++k){
    float mf = Mf[(size_t)k * DIM + d];              // uniform per block
    a0 += filters[(size_t)(4 * r2)     * KF + k] * mf;
    a1 += filters[(size_t)(4 * r2 + 2) * KF + k] * mf;
  }
  unsigned int lo = f2bf(2.f * a0), hi = f2bf(2.f * a1);
  pepkT[(size_t)d * 512 + r2] = lo | (hi << 16);
}

// ---------------- GEMM: x_proj = x @ M_inputs, epilogue writes Bg4 ----------------
// Bg4 elem (b,p,j,d) at u32 index (b*2+p)*1048576 + (j>>2)*4096 + d*4 + (j&3),
// value = y_j | y_{j-1}<<16 (in-stream; y_{-1}=0).  Lane's 4 consecutive j are
// 16B contiguous -> conv loads dwordx4.
#define BM 128
#define BN 128
#define BKK 64
__global__ void k_gemm(const unsigned short* __restrict__ A,
                       const unsigned short* __restrict__ Bt,
                       unsigned int* __restrict__ Bg){
  __shared__ unsigned short As[BM * BKK];   // 16 KB, XOR-swizzled (unit16B ^= row&7)
  __shared__ unsigned short Bs[BN * BKK];   // 16 KB
  int tid  = threadIdx.x;
  int lane = tid & 63, wave = tid >> 6;
  int wm = wave >> 1, wn = wave & 1;
  int trow0 = blockIdx.x * BM;
  int ncol0 = blockIdx.y * BN;

  f32x4 acc[4][4] = {};

  for (int kt = 0; kt < 1024 / BKK; ++kt){
    __syncthreads();
    #pragma unroll
    for (int g = 0; g < 4; ++g){
      int c  = wave * 4 + g;              // chunk 0..15, 1KB each
      int mr = c * 8 + (lane >> 3);       // tile row this lane stages
      int u  = lane & 7;                  // physical 16B unit within row
      int su = u ^ (mr & 7);              // source (logical) unit
      const unsigned short* srcA = A + (size_t)(trow0 + mr) * 1024 + kt * BKK + su * 8;
      gload_lds16(srcA, (char*)As + c * 1024);
      const unsigned short* srcB = Bt + (size_t)(ncol0 + mr) * 1024 + kt * BKK + su * 8;
      gload_lds16(srcB, (char*)Bs + c * 1024);
    }
    __syncthreads();

    bf16x8 af[4][2], bfr[4][2];
    #pragma unroll
    for (int mi = 0; mi < 4; ++mi){
      int row = wm * 64 + mi * 16 + (lane & 15);
      #pragma unroll
      for (int ks = 0; ks < 2; ++ks){
        int u = ((lane >> 4) + 4 * ks) ^ (row & 7);
        af[mi][ks] = *(const bf16x8*)((const char*)As + row * 128 + u * 16);
      }
    }
    #pragma unroll
    for (int ni = 0; ni < 4; ++ni){
      int row = wn * 64 + ni * 16 + (lane & 15);
      #pragma unroll
      for (int ks = 0; ks < 2; ++ks){
        int u = ((lane >> 4) + 4 * ks) ^ (row & 7);
        bfr[ni][ks] = *(const bf16x8*)((const char*)Bs + row * 128 + u * 16);
      }
    }
    #pragma unroll
    for (int mi = 0; mi < 4; ++mi)
      #pragma unroll
      for (int ni = 0; ni < 4; ++ni)
        #pragma unroll
        for (int ks = 0; ks < 2; ++ks)
          acc[mi][ni] = __builtin_amdgcn_mfma_f32_16x16x32_bf16(
              af[mi][ks], bfr[ni][ks], acc[mi][ni], 0, 0, 0);
  }

  unsigned short* Bh = (unsigned short*)Bg;
  #pragma unroll
  for (int mi = 0; mi < 4; ++mi)
    #pragma unroll
    for (int ni = 0; ni < 4; ++ni){
      int col = ncol0 + wn * 64 + ni * 16 + (lane & 15);
      #pragma unroll
      for (int reg = 0; reg < 4; ++reg){
        int row = trow0 + wm * 64 + mi * 16 + (lane >> 4) * 4 + reg;
        unsigned short y = f2bf(acc[mi][ni][reg]);
        int t = row & 2047, bq = row >> 11;
        int p = t & 1, j = t >> 1;
        size_t strm = ((size_t)bq * 2 + p) * 1048576;
        size_t e_lo = strm + (size_t)(j >> 2) * 4096 + (size_t)col * 4 + (j & 3);
        if (j == 0) Bg[e_lo] = (unsigned int)y;        // lo=y, hi=y_{-1}=0
        else        Bh[2 * e_lo] = y;                  // lo half
        if (j < 1023){
          int j1 = j + 1;
          size_t e_hi = strm + (size_t)(j1 >> 2) * 4096 + (size_t)col * 4 + (j1 & 3);
          Bh[2 * e_hi + 1] = y;                        // hi half of entry j+1
        }
      }
    }
}

// ---------------- depthwise causal conv: depth-2 pipeline, counted vmcnt(6) --------
// out[m0+m] = sum_{r<=m0+m} pe[r]*y[m0+m-r], m in [0,32), m0 = 32mt.
// 4-buffer x rotation (B[k] holds quad-group g ≡ k mod 4) + 4-slot pe rotation.
// Chunk c: phase_old (group c-2, in B[(c+2)&3]) -> issue loads for group c+2
// into that SAME vacated buffer + pe chunk c+2 into pv[(c+2)&3] ->
// phase_mid_new (groups c-1, c) -> s_waitcnt vmcnt(6): waits chunk c+1's batch
// (issued last chunk), leaves chunk c+2's 6 loads in flight.  In-flight window
// ~2 chunk-bodies (~2100 cyc) covers HBM first-touch latency that the old
// 1-deep vmcnt(0) scheme stalled on (R10/R16 both 63% VALUBusy).  No pv copies.
// OOB buffer loads return 0 -> free j<0 padding and harmless tail prefetches.
#define BLX4(dst, so) \
  asm volatile("buffer_load_dwordx4 %0, %1, %2, %3 offen" \
               : "=v"(dst) : "v"(voff), "s"(xrsrc), "s"(so))
#define BLP4_0(dst, so) \
  asm volatile("buffer_load_dwordx4 %0, %1, %2, %3 offen" \
               : "=v"(dst) : "v"(pvoff), "s"(prsrc), "s"(so))
#define BLP4_16(dst, so) \
  asm volatile("buffer_load_dwordx4 %0, %1, %2, %3 offen offset:16" \
               : "=v"(dst) : "v"(pvoff), "s"(prsrc), "s"(so))

__device__ __forceinline__ void phase_old(const uint32x4* XBO, const uint32x4* pv,
                                          float* acc){
  #pragma unroll
  for (int q = 0; q < 8; ++q)
    #pragma unroll
    for (int m = 0; m < 32; ++m){
      int idx = m - 2 * q + 16;
      if (idx >= 2 && idx < 16)
        acc[m] = dot2bf(vext(pv[q >> 2], q & 3), vext(XBO[(idx >> 2) & 3], idx & 3),
                        acc[m]);
    }
}
__device__ __forceinline__ void phase_mid_new(const uint32x4* XBM, const uint32x4* XBN,
                                              const uint32x4* pv, float* acc){
  #pragma unroll
  for (int q = 0; q < 8; ++q)
    #pragma unroll
    for (int m = 0; m < 32; ++m){
      int idx = m - 2 * q + 16;
      if (idx >= 16){
        unsigned w = (idx < 32) ? vext(XBM[(idx >> 2) & 3], idx & 3)
                                : vext(XBN[(idx >> 2) & 3], idx & 3);
        acc[m] = dot2bf(vext(pv[q >> 2], q & 3), w, acc[m]);
      }
    }
}

#define BODY4(XBO_, XBM_, XBN_, PVU_, PVL_, C) do{                               \
  phase_old(XBO_, PVU_, acc);                                                    \
  __builtin_amdgcn_sched_barrier(0);                                             \
  { unsigned _xs = (unsigned)(4 * (C) + 8) * 16384u;   /* group C+2 */           \
    BLX4(XBO_[0], _xs);                                                          \
    BLX4(XBO_[1], _xs + 16384u);                                                 \
    BLX4(XBO_[2], _xs + 32768u);                                                 \
    BLX4(XBO_[3], _xs + 49152u);                                                 \
    unsigned _ps = pbase - 32u * (unsigned)((C) + 2);  /* pe chunk C+2 */        \
    BLP4_0(PVL_[0], _ps); BLP4_16(PVL_[1], _ps); }                               \
  __builtin_amdgcn_sched_barrier(0);                                             \
  phase_mid_new(XBM_, XBN_, PVU_, acc);                                          \
  asm volatile("s_waitcnt vmcnt(6)" ::: "memory");                               \
  __builtin_amdgcn_sched_barrier(0);                                             \
}while(0)

__global__ __launch_bounds__(256, 3)
void k_conv(const unsigned int* __restrict__ Bg,     // Bg4 interleaved (see k_gemm)
            const unsigned int* __restrict__ pepkT,  // [1024][512] packed pe pairs
            float* __restrict__ out){                // [4][2048][1024] f32
  int tid  = threadIdx.x;
  int bid  = blockIdx.x;                    // 0..1023
  int bp   = bid & 7;                       // XCD pin: stream -> one XCD
  int rest = bid >> 3;                      // 0..127
  int dblk = rest & 3;
  int mt   = 31 - (rest >> 2);              // LPT: longest tiles dispatch first
  int b = bp >> 1, p = bp & 1;
  int d = dblk * 256 + tid;                 // 0..1023

  uint32x4 xrsrc = make_srsrc(Bg + (size_t)bp * 1048576, 4194304u);  // 4MB stream
  uint32x4 prsrc = make_srsrc(pepkT, 2097152u);

  unsigned voff  = (unsigned)(d * 16);      // lane's 16B within a quad row
  unsigned pvoff = (unsigned)(d * 2048);

  uint32x4 B0[4], B1[4], B2[4], B3[4];
  uint32x4 pv0[2], pv1[2], pv2[2], pv3[2];
  float acc[32];

  unsigned pbase = 64u * (unsigned)mt + 32u;  // pe byte soffset of chunk 0
  int nch = 2 * mt + 2;

  #pragma unroll
  for (int m = 0; m < 32; ++m) acc[m] = 0.f;

  // prologue: groups -2,-1 (OOB -> 0), 0, 1 and pe chunks 0, 1
  #pragma unroll
  for (int k = 0; k < 4; ++k) BLX4(B2[k], (unsigned)(k - 8) * 16384u);  // group -2
  #pragma unroll
  for (int k = 0; k < 4; ++k) BLX4(B3[k], (unsigned)(k - 4) * 16384u);  // group -1
  #pragma unroll
  for (int k = 0; k < 4; ++k) BLX4(B0[k], (unsigned)k * 16384u);        // group 0
  #pragma unroll
  for (int k = 0; k < 4; ++k) BLX4(B1[k], (unsigned)(k + 4) * 16384u);  // group 1
  BLP4_0(pv0[0], pbase);        BLP4_16(pv0[1], pbase);         // pe chunk 0
  BLP4_0(pv1[0], pbase - 32u);  BLP4_16(pv1[1], pbase - 32u);   // pe chunk 1
  asm volatile("s_waitcnt vmcnt(0)" ::: "memory");
  __builtin_amdgcn_sched_barrier(0);

  int c = 0;
  for (;;){
    BODY4(B2, B3, B0, pv0, pv2, c); if (++c == nch) break;
    BODY4(B3, B0, B1, pv1, pv3, c); if (++c == nch) break;
    BODY4(B0, B1, B2, pv2, pv0, c); if (++c == nch) break;
    BODY4(B1, B2, B3, pv3, pv1, c); if (++c == nch) break;
  }

  float* oc = out + ((size_t)(b * SEQ + p) * 1024 + d) + (size_t)mt * 32 * 2048;
  #pragma unroll
  for (int m = 0; m < 32; ++m) oc[(size_t)m * 2048] = acc[m];
}

extern "C" void kernel_launch(void* const* d_in, const int* in_sizes, int n_in,
                              void* d_out, int out_size, void* d_ws, size_t ws_size,
                              hipStream_t stream){
  const float* x       = (const float*)d_in[0];
  const float* filters = (const float*)d_in[1];
  const float* Mi      = (const float*)d_in[2];
  const float* Mf      = (const float*)d_in[3];

  char* ws = (char*)d_ws;
  unsigned short* Xb    = (unsigned short*)(ws);                              // 16 MB
  unsigned int*   Bg    = (unsigned int*)  (ws + (size_t)16 * 1024 * 1024);   // 32 MB
  unsigned short* MbT   = (unsigned short*)(ws + (size_t)48 * 1024 * 1024);   //  2 MB
  unsigned int*   pepkT = (unsigned int*)  (ws + (size_t)50 * 1024 * 1024);   //  2 MB
  float* out = (float*)d_out;

  hipLaunchKernelGGL(k_cvt_x, dim3(8192), dim3(256), 0, stream, x, Xb);
  hipLaunchKernelGGL(k_tr_M,  dim3(32, 32), dim3(32, 8), 0, stream, Mi, MbT);
  hipLaunchKernelGGL(k_pe,    dim3(2, 1024), dim3(256), 0, stream, filters, Mf, pepkT);
  hipLaunchKernelGGL(k_gemm,  dim3(64, 8), dim3(256), 0, stream, Xb, MbT, Bg);
  hipLaunchKernelGGL(k_conv,  dim3(1024), dim3(256), 0, stream, Bg, pepkT, out);
}

// Round 18
// 128.884 us; speedup vs baseline: 1.0787x; 1.0787x over previous
//
#include <hip/hip_runtime.h>
#include <hip/hip_bf16.h>
#include <stdint.h>
#include <stddef.h>

#define DIM 1024
#define SEQ 2048
#define KF 24

using f32x4    = __attribute__((ext_vector_type(4))) float;
using bf16x8   = __attribute__((ext_vector_type(8))) short;
using uint32x4 = __attribute__((ext_vector_type(4))) unsigned int;

__device__ __forceinline__ unsigned short f2bf(float f){
  union { float f; unsigned int i; } v; v.f = f;
  unsigned int r = v.i + 0x7FFFu + ((v.i >> 16) & 1u);  // RNE
  return (unsigned short)(r >> 16);
}
// D = a.bf16[0]*b.bf16[0] + a.bf16[1]*b.bf16[1] + c   (V_DOT2_F32_BF16, VOP3P)
__device__ __forceinline__ float dot2bf(unsigned int a, unsigned int b, float c){
  float d;
  asm("v_dot2_f32_bf16 %0, %1, %2, %3" : "=v"(d) : "v"(a), "v"(b), "v"(c));
  return d;
}
__device__ __forceinline__ unsigned vext(const uint32x4 v, int i){
  return i == 0 ? v.x : i == 1 ? v.y : i == 2 ? v.z : v.w;
}
__device__ __forceinline__ void gload_lds16(const void* g, void* l){
  __builtin_amdgcn_global_load_lds(
      (const __attribute__((address_space(1))) unsigned int*)g,
      (__attribute__((address_space(3))) unsigned int*)l, 16, 0, 0);
}
__device__ __forceinline__ uint32x4 make_srsrc(const void* base, unsigned bytes){
  uint32x4 r;
  r.x = (unsigned)(uintptr_t)base;
  r.y = (unsigned)((uintptr_t)base >> 32);   // stride=0
  r.z = bytes;                               // num_records (bytes); OOB loads -> 0
  r.w = 0x00020000u;                         // raw untyped dword
  return r;
}

// ---------------- prep: x fp32 -> bf16 ----------------
__global__ void k_cvt_x(const float* __restrict__ x, unsigned short* __restrict__ xb){
  int i = blockIdx.x * 256 + threadIdx.x;            // each thread 4 elems
  const float4* x4 = (const float4*)x;
  float4 v = x4[i];
  ushort4 o;
  o.x = f2bf(v.x); o.y = f2bf(v.y); o.z = f2bf(v.z); o.w = f2bf(v.w);
  *(ushort4*)(xb + (size_t)i * 4) = o;
}

// ---------------- prep: M_inputs transpose -> bf16 (B^T, [d][e]) ----------------
__global__ void k_tr_M(const float* __restrict__ Mi, unsigned short* __restrict__ MbT){
  __shared__ float tile[32][33];
  int e0 = blockIdx.y * 32, d0 = blockIdx.x * 32;
  int tx = threadIdx.x, ty = threadIdx.y;            // block (32,8)
  #pragma unroll
  for (int r = 0; r < 32; r += 8)
    tile[ty + r][tx] = Mi[(size_t)(e0 + ty + r) * DIM + d0 + tx];
  __syncthreads();
  #pragma unroll
  for (int r = 0; r < 32; r += 8)
    MbT[(size_t)(d0 + ty + r) * DIM + e0 + tx] = f2bf(tile[tx][ty + r]);
}

// ---------------- prep: pe packed pairs, CHUNK-INTERLEAVED [k][d][8] ----------------
// pepk2[k][d][i] = u32{ lo = 2*phi[2r][d], hi = 2*phi[2r+1... ] } for r2 = 8k+i,
// i.e. pair (pe[2*r2], pe[2*r2+1]).  A lane's per-chunk 8 pairs are 32B
// contiguous -> conv pe loads are wave-coalesced (2KB/wave, 2 dwordx4).
__global__ void k_pe(const float* __restrict__ filters, const float* __restrict__ Mf,
                     unsigned int* __restrict__ pepk2){
  int r2 = blockIdx.x * 256 + threadIdx.x;           // 0..511 (grid.x = 2)
  int d  = blockIdx.y;                               // 0..1023
  float a0 = 0.f, a1 = 0.f;
  #pragma unroll
  for (int k = 0; k < KF; ++k){
    float mf = Mf[(size_t)k * DIM + d];              // uniform per block
    a0 += filters[(size_t)(4 * r2)     * KF + k] * mf;
    a1 += filters[(size_t)(4 * r2 + 2) * KF + k] * mf;
  }
  unsigned int lo = f2bf(2.f * a0), hi = f2bf(2.f * a1);
  pepk2[(size_t)(r2 >> 3) * 8192 + (size_t)d * 8 + (r2 & 7)] = lo | (hi << 16);
}

// ---------------- GEMM: x_proj = x @ M_inputs, epilogue writes Bg4 ----------------
// Bg4 elem (b,p,j,d) at u32 index (b*2+p)*1048576 + (j>>2)*4096 + d*4 + (j&3),
// value = y_j | y_{j-1}<<16 (in-stream; y_{-1}=0).  Lane's 4 consecutive j are
// 16B contiguous -> conv loads dwordx4.
#define BM 128
#define BN 128
#define BKK 64
__global__ void k_gemm(const unsigned short* __restrict__ A,
                       const unsigned short* __restrict__ Bt,
                       unsigned int* __restrict__ Bg){
  __shared__ unsigned short As[BM * BKK];   // 16 KB, XOR-swizzled (unit16B ^= row&7)
  __shared__ unsigned short Bs[BN * BKK];   // 16 KB
  int tid  = threadIdx.x;
  int lane = tid & 63, wave = tid >> 6;
  int wm = wave >> 1, wn = wave & 1;
  int trow0 = blockIdx.x * BM;
  int ncol0 = blockIdx.y * BN;

  f32x4 acc[4][4] = {};

  for (int kt = 0; kt < 1024 / BKK; ++kt){
    __syncthreads();
    #pragma unroll
    for (int g = 0; g < 4; ++g){
      int c  = wave * 4 + g;              // chunk 0..15, 1KB each
      int mr = c * 8 + (lane >> 3);       // tile row this lane stages
      int u  = lane & 7;                  // physical 16B unit within row
      int su = u ^ (mr & 7);              // source (logical) unit
      const unsigned short* srcA = A + (size_t)(trow0 + mr) * 1024 + kt * BKK + su * 8;
      gload_lds16(srcA, (char*)As + c * 1024);
      const unsigned short* srcB = Bt + (size_t)(ncol0 + mr) * 1024 + kt * BKK + su * 8;
      gload_lds16(srcB, (char*)Bs + c * 1024);
    }
    __syncthreads();

    bf16x8 af[4][2], bfr[4][2];
    #pragma unroll
    for (int mi = 0; mi < 4; ++mi){
      int row = wm * 64 + mi * 16 + (lane & 15);
      #pragma unroll
      for (int ks = 0; ks < 2; ++ks){
        int u = ((lane >> 4) + 4 * ks) ^ (row & 7);
        af[mi][ks] = *(const bf16x8*)((const char*)As + row * 128 + u * 16);
      }
    }
    #pragma unroll
    for (int ni = 0; ni < 4; ++ni){
      int row = wn * 64 + ni * 16 + (lane & 15);
      #pragma unroll
      for (int ks = 0; ks < 2; ++ks){
        int u = ((lane >> 4) + 4 * ks) ^ (row & 7);
        bfr[ni][ks] = *(const bf16x8*)((const char*)Bs + row * 128 + u * 16);
      }
    }
    #pragma unroll
    for (int mi = 0; mi < 4; ++mi)
      #pragma unroll
      for (int ni = 0; ni < 4; ++ni)
        #pragma unroll
        for (int ks = 0; ks < 2; ++ks)
          acc[mi][ni] = __builtin_amdgcn_mfma_f32_16x16x32_bf16(
              af[mi][ks], bfr[ni][ks], acc[mi][ni], 0, 0, 0);
  }

  unsigned short* Bh = (unsigned short*)Bg;
  #pragma unroll
  for (int mi = 0; mi < 4; ++mi)
    #pragma unroll
    for (int ni = 0; ni < 4; ++ni){
      int col = ncol0 + wn * 64 + ni * 16 + (lane & 15);
      #pragma unroll
      for (int reg = 0; reg < 4; ++reg){
        int row = trow0 + wm * 64 + mi * 16 + (lane >> 4) * 4 + reg;
        unsigned short y = f2bf(acc[mi][ni][reg]);
        int t = row & 2047, bq = row >> 11;
        int p = t & 1, j = t >> 1;
        size_t strm = ((size_t)bq * 2 + p) * 1048576;
        size_t e_lo = strm + (size_t)(j >> 2) * 4096 + (size_t)col * 4 + (j & 3);
        if (j == 0) Bg[e_lo] = (unsigned int)y;        // lo=y, hi=y_{-1}=0
        else        Bh[2 * e_lo] = y;                  // lo half
        if (j < 1023){
          int j1 = j + 1;
          size_t e_hi = strm + (size_t)(j1 >> 2) * 4096 + (size_t)col * 4 + (j1 & 3);
          Bh[2 * e_hi + 1] = y;                        // hi half of entry j+1
        }
      }
    }
}

// ---------------- depthwise causal conv: R16 body + COALESCED pe loads -------------
// out[m0+m] = sum_{r<=m0+m} pe[r]*y[m0+m-r], m in [0,32), one tile per block.
// Body identical to passing R16: phase_old (56 dot2) -> prefetch 4 x-quads + 2
// pe dwordx4 into vacated buffer -> phase_mid_new (200 dot2) -> vmcnt(0).
// ONLY change: pe reads use pepk2[k][d][8] (pvoff=d*32, chunk stride 32768B) so
// each pe instruction is wave-coalesced (2KB contiguous, ~16 txns) instead of
// 64-line gather (~64 txns) -> per-chunk TA cost 192 -> 96 cyc, unblocking the
// vmcnt queue stall that kept VALUBusy at 63% across R10/R16/R17.
#define BLX4(dst, so) \
  asm volatile("buffer_load_dwordx4 %0, %1, %2, %3 offen" \
               : "=v"(dst) : "v"(voff), "s"(xrsrc), "s"(so))
#define BLP4_0(dst, so) \
  asm volatile("buffer_load_dwordx4 %0, %1, %2, %3 offen" \
               : "=v"(dst) : "v"(pvoff), "s"(prsrc), "s"(so))
#define BLP4_16(dst, so) \
  asm volatile("buffer_load_dwordx4 %0, %1, %2, %3 offen offset:16" \
               : "=v"(dst) : "v"(pvoff), "s"(prsrc), "s"(so))

__device__ __forceinline__ void phase_old(const uint32x4* XBO, const uint32x4* pv,
                                          float* acc){
  #pragma unroll
  for (int q = 0; q < 8; ++q)
    #pragma unroll
    for (int m = 0; m < 32; ++m){
      int idx = m - 2 * q + 16;
      if (idx >= 2 && idx < 16)
        acc[m] = dot2bf(vext(pv[q >> 2], q & 3), vext(XBO[(idx >> 2) & 3], idx & 3),
                        acc[m]);
    }
}
__device__ __forceinline__ void phase_mid_new(const uint32x4* XBM, const uint32x4* XBN,
                                              const uint32x4* pv, float* acc){
  #pragma unroll
  for (int q = 0; q < 8; ++q)
    #pragma unroll
    for (int m = 0; m < 32; ++m){
      int idx = m - 2 * q + 16;
      if (idx >= 16){
        unsigned w = (idx < 32) ? vext(XBM[(idx >> 2) & 3], idx & 3)
                                : vext(XBN[(idx >> 2) & 3], idx & 3);
        acc[m] = dot2bf(vext(pv[q >> 2], q & 3), w, acc[m]);
      }
    }
}

#define BODY(XBO_, XBM_, XBN_, C) do{                                            \
  phase_old(XBO_, pv, acc);                                                      \
  __builtin_amdgcn_sched_barrier(0);                                             \
  { unsigned _xs = (unsigned)(4 * (C) + 4) * 16384u;                             \
    BLX4(XBO_[0], _xs);                                                          \
    BLX4(XBO_[1], _xs + 16384u);                                                 \
    BLX4(XBO_[2], _xs + 32768u);                                                 \
    BLX4(XBO_[3], _xs + 49152u);                                                 \
    unsigned _ps = pbase - 32768u * (unsigned)((C) + 1);                         \
    BLP4_0(npv[0], _ps); BLP4_16(npv[1], _ps); }                                 \
  __builtin_amdgcn_sched_barrier(0);                                             \
  phase_mid_new(XBM_, XBN_, pv, acc);                                            \
  asm volatile("s_waitcnt vmcnt(0)" ::: "memory");                               \
  __builtin_amdgcn_sched_barrier(0);                                             \
  pv[0] = npv[0]; pv[1] = npv[1];                                                \
}while(0)

__global__ __launch_bounds__(256, 4)
void k_conv(const unsigned int* __restrict__ Bg,     // Bg4 interleaved (see k_gemm)
            const unsigned int* __restrict__ pepk2,  // [64][1024][8] pe pairs
            float* __restrict__ out){                // [4][2048][1024] f32
  int tid  = threadIdx.x;
  int bid  = blockIdx.x;                    // 0..1023
  int bp   = bid & 7;                       // XCD pin: stream -> one XCD
  int rest = bid >> 3;                      // 0..127
  int dblk = rest & 3;
  int mt   = 31 - (rest >> 2);              // LPT: longest tiles dispatch first
  int b = bp >> 1, p = bp & 1;
  int d = dblk * 256 + tid;                 // 0..1023

  uint32x4 xrsrc = make_srsrc(Bg + (size_t)bp * 1048576, 4194304u);  // 4MB stream
  uint32x4 prsrc = make_srsrc(pepk2, 2097152u);

  unsigned voff  = (unsigned)(d * 16);      // lane's 16B within a quad row
  unsigned pvoff = (unsigned)(d * 32);      // lane's 32B pe record within a chunk

  uint32x4 B0[4], B1[4], B2[4], pv[2], npv[2];
  float acc[32];

  unsigned pbase = (2u * (unsigned)mt + 1u) * 32768u;  // pe chunk-0 byte offset
  int nch = 2 * mt + 2;

  #pragma unroll
  for (int m = 0; m < 32; ++m) acc[m] = 0.f;

  // prologue: chunk-0 window quads -8..3 (negatives OOB -> 0) + pe
  #pragma unroll
  for (int k = 0; k < 4; ++k) BLX4(B0[k], (unsigned)(k - 8) * 16384u);
  #pragma unroll
  for (int k = 0; k < 4; ++k) BLX4(B1[k], (unsigned)(k - 4) * 16384u);
  #pragma unroll
  for (int k = 0; k < 4; ++k) BLX4(B2[k], (unsigned)k * 16384u);
  BLP4_0(pv[0], pbase); BLP4_16(pv[1], pbase);
  asm volatile("s_waitcnt vmcnt(0)" ::: "memory");
  __builtin_amdgcn_sched_barrier(0);

  int c = 0;
  for (;;){
    BODY(B0, B1, B2, c); if (++c == nch) break;
    BODY(B1, B2, B0, c); if (++c == nch) break;
    BODY(B2, B0, B1, c); if (++c == nch) break;
  }

  float* oc = out + ((size_t)(b * SEQ + p) * 1024 + d) + (size_t)mt * 32 * 2048;
  #pragma unroll
  for (int m = 0; m < 32; ++m) oc[(size_t)m * 2048] = acc[m];
}

extern "C" void kernel_launch(void* const* d_in, const int* in_sizes, int n_in,
                              void* d_out, int out_size, void* d_ws, size_t ws_size,
                              hipStream_t stream){
  const float* x       = (const float*)d_in[0];
  const float* filters = (const float*)d_in[1];
  const float* Mi      = (const float*)d_in[2];
  const float* Mf      = (const float*)d_in[3];

  char* ws = (char*)d_ws;
  unsigned short* Xb    = (unsigned short*)(ws);                              // 16 MB
  unsigned int*   Bg    = (unsigned int*)  (ws + (size_t)16 * 1024 * 1024);   // 32 MB
  unsigned short* MbT   = (unsigned short*)(ws + (size_t)48 * 1024 * 1024);   //  2 MB
  unsigned int*   pepk2 = (unsigned int*)  (ws + (size_t)50 * 1024 * 1024);   //  2 MB
  float* out = (float*)d_out;

  hipLaunchKernelGGL(k_cvt_x, dim3(8192), dim3(256), 0, stream, x, Xb);
  hipLaunchKernelGGL(k_tr_M,  dim3(32, 32), dim3(32, 8), 0, stream, Mi, MbT);
  hipLaunchKernelGGL(k_pe,    dim3(2, 1024), dim3(256), 0, stream, filters, Mf, pepk2);
  hipLaunchKernelGGL(k_gemm,  dim3(64, 8), dim3(256), 0, stream, Xb, MbT, Bg);
  // 65536 B dynamic LDS per block: caps residency at 2 blocks/CU (160 KiB pool)
  // -> 512 resident slots serve 1024 LPT-ordered blocks with HW backfill.
  hipLaunchKernelGGL(k_conv,  dim3(1024), dim3(256), 65536, stream, Bg, pepk2, out);
}